// Round 1
// baseline (263.997 us; speedup 1.0000x reference)
//
#include <hip/hip_runtime.h>
#include <math.h>

#define N_ATOMS    30000
#define N_PAIRS    300000
#define NF         64
#define ND         20
#define K_ENV      1280            // ND*NF
#define K_TOT      1344            // K_ENV + NF (self features appended)
#define NKSTEP     42              // K_TOT / 32
#define HARD_CUT   6.5f
#define BA         16              // atoms per block in main kernel
#define ESTRIDE    1352            // padded env row stride in bf16 units (1344+8)

typedef short  s16x8  __attribute__((ext_vector_type(8)));
typedef __bf16 bf16x8 __attribute__((ext_vector_type(8)));
typedef float  f32x4  __attribute__((ext_vector_type(4)));

__device__ __forceinline__ unsigned short f2bf(float x) {
    union { float f; unsigned u; } v; v.f = x;
    unsigned r = v.u + 0x7fffu + ((v.u >> 16) & 1u);   // round-to-nearest-even
    return (unsigned short)(r >> 16);
}

// ---------------------------------------------------------------------------
// K0: pack interaction weights + self weights into bf16 B-fragment layout.
// WtB[((ks*4 + q)*64 + lane)*8 + j] = W[k = ks*32 + (lane>>4)*8 + j][o = q*16 + (lane&15)]
// where W[k][o] = int_weights[k>>6][o][k&63] for k<1280, else w_self[o][k-1280].
__global__ void k_pack_w(const float* __restrict__ iw, const float* __restrict__ wself,
                         unsigned short* __restrict__ WtB) {
    int idx = blockIdx.x * 256 + threadIdx.x;       // (ks*4+q)*64 + lane
    if (idx >= NKSTEP * 4 * 64) return;
    int l  = idx & 63;
    int q  = (idx >> 6) & 3;
    int ks = idx >> 8;
    int n  = q * 16 + (l & 15);
    int kb = ks * 32 + (l >> 4) * 8;
    union { unsigned short us[8]; uint4 v; } u;
    #pragma unroll
    for (int j = 0; j < 8; j++) {
        int k = kb + j;
        float val;
        if (k < K_ENV) val = iw[((k >> 6) * NF + n) * NF + (k & 63)];
        else           val = wself[n * NF + (k - K_ENV)];
        u.us[j] = f2bf(val);
    }
    *(uint4*)&WtB[idx * 8] = u.v;
}

// ---------------------------------------------------------------------------
__global__ void k_zero(int* __restrict__ p, int n) {
    int i = blockIdx.x * 256 + threadIdx.x;
    if (i < n) p[i] = 0;
}

__global__ void k_hist(const int* __restrict__ first, int* __restrict__ counts) {
    int p = blockIdx.x * 256 + threadIdx.x;
    if (p < N_PAIRS) atomicAdd(&counts[first[p]], 1);
}

// Exclusive scan of counts[30000] -> offsets[30001]. Single block, 1024 threads.
__global__ void k_scan(const int* __restrict__ counts, int* __restrict__ offsets) {
    __shared__ int lds[1024];
    const int t = threadIdx.x;
    const int CH = 30;                       // 1024*30 = 30720 >= 30000
    int beg = t * CH;
    int end = min(beg + CH, N_ATOMS);
    int s = 0;
    for (int i = beg; i < end; i++) s += counts[i];
    lds[t] = s;
    __syncthreads();
    for (int d = 1; d < 1024; d <<= 1) {
        int v = (t >= d) ? lds[t - d] : 0;
        __syncthreads();
        lds[t] += v;
        __syncthreads();
    }
    int base = lds[t] - s;                   // exclusive prefix of this chunk
    for (int i = beg; i < end; i++) { offsets[i] = base; base += counts[i]; }
    if (t == 1023) offsets[N_ATOMS] = lds[1023];
}

// ---------------------------------------------------------------------------
// K3: compute sensitivities and scatter pairs into CSR (sorted) order.
__global__ void k_sense_scatter(const int* __restrict__ first, const int* __restrict__ second,
                                const float* __restrict__ dist, const float* __restrict__ mu,
                                const float* __restrict__ sigma,
                                const int* __restrict__ offsets, int* __restrict__ cursor,
                                int* __restrict__ s_second, float* __restrict__ s_sense) {
    int p = blockIdx.x * 256 + threadIdx.x;
    if (p >= N_PAIRS) return;
    int a = first[p];
    int pos = offsets[a] + atomicAdd(&cursor[a], 1);
    s_second[pos] = second[p];
    float d   = dist[p];
    float inv = 1.0f / d;
    float c   = cosf(0.5f * 3.14159265358979323846f * d / HARD_CUT);
    float cut = (d < HARD_CUT) ? c * c : 0.0f;
    float* sr = &s_sense[(size_t)pos * ND];
    #pragma unroll
    for (int nu = 0; nu < ND; nu++) {
        float z = (inv - mu[nu]) / sigma[nu];
        sr[nu] = __expf(-0.5f * z * z) * cut;
    }
}

// ---------------------------------------------------------------------------
// K4: fused envsum + interaction matmul + self term.
// Phase 1: wave w accumulates env rows for atoms 4w..4w+3 (lane = feature,
//          20 nu in registers), writes bf16 rows to LDS (self features appended).
// Phase 2: MFMA 16x16x32 bf16: out[16 atoms][64] = env[16][1344] x W[1344][64].
__global__ void __launch_bounds__(256, 3)
k_main(const float* __restrict__ x, const int* __restrict__ offsets,
       const int* __restrict__ s_second, const float* __restrict__ s_sense,
       const unsigned short* __restrict__ WtB, const float* __restrict__ bself,
       float* __restrict__ out) {
    __shared__ unsigned short env[BA * ESTRIDE];
    const int t  = threadIdx.x;
    const int w  = t >> 6;       // wave 0..3
    const int l  = t & 63;       // lane
    const int a0 = blockIdx.x * BA;

    // ---- Phase 1: envsum ----
    for (int c = 0; c < 4; c++) {
        const int i = 4 * w + c;
        const int a = a0 + i;
        const int beg = offsets[a];
        const int end = offsets[a + 1];
        float acc[ND];
        #pragma unroll
        for (int m = 0; m < ND; m++) acc[m] = 0.0f;

        // software-prefetch neighbor feature one pair ahead
        float nvn = 0.0f;
        if (beg < end) { int b0 = s_second[beg]; nvn = x[b0 * NF + l]; }
        for (int j = beg; j < end; j++) {
            float nv = nvn;
            if (j + 1 < end) { int b2 = s_second[j + 1]; nvn = x[b2 * NF + l]; }
            const float* sr = &s_sense[(size_t)j * ND];
            #pragma unroll
            for (int m = 0; m < ND; m++) acc[m] += sr[m] * nv;
        }
        unsigned short* er = &env[i * ESTRIDE];
        #pragma unroll
        for (int m = 0; m < ND; m++) er[l + 64 * m] = f2bf(acc[m]);
        er[K_ENV + l] = f2bf(x[a * NF + l]);   // self features as extra K rows
    }
    __syncthreads();

    // ---- Phase 2: MFMA GEMM ----
    const int m16  = l & 15;     // A-row / C-col index
    const int quad = l >> 4;
    f32x4 acc = {0.f, 0.f, 0.f, 0.f};
    for (int ks = 0; ks < NKSTEP; ks++) {
        s16x8 afrag = *(const s16x8*)&env[m16 * ESTRIDE + ks * 32 + quad * 8];
        s16x8 bfrag = *(const s16x8*)&WtB[((ks * 4 + w) * 64 + l) * 8];
        acc = __builtin_amdgcn_mfma_f32_16x16x32_bf16(
                  __builtin_bit_cast(bf16x8, afrag),
                  __builtin_bit_cast(bf16x8, bfrag), acc, 0, 0, 0);
    }
    const float bs = bself[w * 16 + m16];
    #pragma unroll
    for (int r = 0; r < 4; r++) {
        int row = quad * 4 + r;                       // atom within block
        out[(size_t)(a0 + row) * NF + w * 16 + m16] = acc[r] + bs;
    }
}

// ---------------------------------------------------------------------------
extern "C" void kernel_launch(void* const* d_in, const int* in_sizes, int n_in,
                              void* d_out, int out_size, void* d_ws, size_t ws_size,
                              hipStream_t stream) {
    const float* x      = (const float*)d_in[0];
    const int*   first  = (const int*)d_in[1];
    const int*   second = (const int*)d_in[2];
    const float* dist   = (const float*)d_in[3];
    const float* mu     = (const float*)d_in[4];
    const float* sigma  = (const float*)d_in[5];
    const float* iw     = (const float*)d_in[6];
    const float* wself  = (const float*)d_in[7];
    const float* bself  = (const float*)d_in[8];
    float* out = (float*)d_out;

    char* ws = (char*)d_ws;
    unsigned short* WtB   = (unsigned short*)(ws);              // 172032 B
    int*   counts   = (int*)(ws + 172032);                      // 120000 B
    int*   cursor   = (int*)(ws + 292032);                      // 120000 B (adjacent to counts)
    int*   offsets  = (int*)(ws + 412032);                      // 120004 B
    int*   s_second = (int*)(ws + 532096);                      // 1200000 B
    float* s_sense  = (float*)(ws + 1732096);                   // 24000000 B -> total ~25.7 MB

    k_pack_w<<<dim3(42), dim3(256), 0, stream>>>(iw, wself, WtB);
    k_zero<<<dim3((60000 + 255) / 256), dim3(256), 0, stream>>>(counts, 60000);
    k_hist<<<dim3((N_PAIRS + 255) / 256), dim3(256), 0, stream>>>(first, counts);
    k_scan<<<dim3(1), dim3(1024), 0, stream>>>(counts, offsets);
    k_sense_scatter<<<dim3((N_PAIRS + 255) / 256), dim3(256), 0, stream>>>(
        first, second, dist, mu, sigma, offsets, cursor, s_second, s_sense);
    k_main<<<dim3(N_ATOMS / BA), dim3(256), 0, stream>>>(
        x, offsets, s_second, s_sense, WtB, bself, out);
}

// Round 2
// 219.550 us; speedup vs baseline: 1.2024x; 1.2024x over previous
//
#include <hip/hip_runtime.h>
#include <math.h>

#define N_ATOMS    30000
#define N_PAIRS    300000
#define PAD_MAX    420000          // >= 300000 + 3*30000 padded CSR slots
#define NF         64
#define ND         20
#define K_ENV      1280            // ND*NF
#define K_TOT      1344            // K_ENV + NF (self features appended)
#define NKSTEP     42              // K_TOT / 32
#define HARD_CUT   6.5f
#define BA         16              // atoms per block in main kernel
#define ESTRIDE    1352            // padded env row stride in bf16 units (1344+8)

typedef short  s16x8  __attribute__((ext_vector_type(8)));
typedef __bf16 bf16x8 __attribute__((ext_vector_type(8)));
typedef float  f32x4  __attribute__((ext_vector_type(4)));

__device__ __forceinline__ unsigned short f2bf(float x) {
    union { float f; unsigned u; } v; v.f = x;
    unsigned r = v.u + 0x7fffu + ((v.u >> 16) & 1u);   // round-to-nearest-even
    return (unsigned short)(r >> 16);
}
__device__ __forceinline__ float bf_lo(unsigned u) {
    union { unsigned u; float f; } v; v.u = u << 16; return v.f;
}
__device__ __forceinline__ float bf_hi(unsigned u) {
    union { unsigned u; float f; } v; v.u = u & 0xffff0000u; return v.f;
}

// ---------------------------------------------------------------------------
// K0: pack interaction weights + self weights into bf16 B-fragment layout.
// WtB[((ks*4 + q)*64 + lane)*8 + j] = W[k = ks*32 + (lane>>4)*8 + j][o = q*16 + (lane&15)]
__global__ void k_pack_w(const float* __restrict__ iw, const float* __restrict__ wself,
                         unsigned short* __restrict__ WtB) {
    int idx = blockIdx.x * 256 + threadIdx.x;       // (ks*4+q)*64 + lane
    if (idx >= NKSTEP * 4 * 64) return;
    int l  = idx & 63;
    int q  = (idx >> 6) & 3;
    int ks = idx >> 8;
    int n  = q * 16 + (l & 15);
    int kb = ks * 32 + (l >> 4) * 8;
    union { unsigned short us[8]; uint4 v; } u;
    #pragma unroll
    for (int j = 0; j < 8; j++) {
        int k = kb + j;
        float val;
        if (k < K_ENV) val = iw[((k >> 6) * NF + n) * NF + (k & 63)];
        else           val = wself[n * NF + (k - K_ENV)];
        u.us[j] = f2bf(val);
    }
    *(uint4*)&WtB[idx * 8] = u.v;
}

// ---------------------------------------------------------------------------
// K1: init workspace (re-poisoned to 0xAA before every call).
__global__ void k_init(int* __restrict__ counts_cursor, int* __restrict__ s_second,
                       float* __restrict__ s_dist) {
    int i = blockIdx.x * 256 + threadIdx.x;
    if (i < PAD_MAX) { s_second[i] = 0; s_dist[i] = 1.0e9f; }
    if (i < 2 * N_ATOMS) counts_cursor[i] = 0;
}

__global__ void k_hist(const int* __restrict__ first, int* __restrict__ counts) {
    int p = blockIdx.x * 256 + threadIdx.x;
    if (p < N_PAIRS) atomicAdd(&counts[first[p]], 1);
}

// Exclusive scan of pad4(counts[30000]) -> offsets[30001]. Single block.
__global__ void k_scan(const int* __restrict__ counts, int* __restrict__ offsets) {
    __shared__ int lds[1024];
    const int t = threadIdx.x;
    const int CH = 30;                       // 1024*30 = 30720 >= 30000
    int beg = t * CH;
    int end = min(beg + CH, N_ATOMS);
    int s = 0;
    for (int i = beg; i < end; i++) s += (counts[i] + 3) & ~3;
    lds[t] = s;
    __syncthreads();
    for (int d = 1; d < 1024; d <<= 1) {
        int v = (t >= d) ? lds[t - d] : 0;
        __syncthreads();
        lds[t] += v;
        __syncthreads();
    }
    int base = lds[t] - s;                   // exclusive prefix of this chunk
    for (int i = beg; i < end; i++) { offsets[i] = base; base += (counts[i] + 3) & ~3; }
    if (t == 1023) offsets[N_ATOMS] = lds[1023];
}

// ---------------------------------------------------------------------------
// K3: scatter pairs into padded CSR order (8B per pair, vs 84B before).
__global__ void k_scatter(const int* __restrict__ first, const int* __restrict__ second,
                          const float* __restrict__ dist,
                          const int* __restrict__ offsets, int* __restrict__ cursor,
                          int* __restrict__ s_second, float* __restrict__ s_dist) {
    int p = blockIdx.x * 256 + threadIdx.x;
    if (p >= N_PAIRS) return;
    int a = first[p];
    int pos = offsets[a] + atomicAdd(&cursor[a], 1);
    s_second[pos] = second[p];
    s_dist[pos]   = dist[p];
}

// ---------------------------------------------------------------------------
// K4: sensitivities in sorted order, coalesced bf16 writes (dummies -> 0).
__global__ void k_sense(const float* __restrict__ s_dist, const float* __restrict__ mu,
                        const float* __restrict__ sigma, unsigned short* __restrict__ s_sense) {
    int p = blockIdx.x * 256 + threadIdx.x;
    if (p >= PAD_MAX) return;
    float d   = s_dist[p];
    float inv = 1.0f / d;
    float c   = __cosf(0.5f * 3.14159265358979323846f * d / HARD_CUT);
    float cut = (d < HARD_CUT) ? c * c : 0.0f;
    unsigned short sv[ND];
    #pragma unroll
    for (int nu = 0; nu < ND; nu++) {
        float z = (inv - mu[nu]) / sigma[nu];
        sv[nu] = f2bf(__expf(-0.5f * z * z) * cut);
    }
    uint2* dst = (uint2*)(s_sense + (size_t)p * ND);   // 40B, 8-aligned
    #pragma unroll
    for (int w = 0; w < 5; w++) {
        uint2 v;
        v.x = (unsigned)sv[4 * w + 0] | ((unsigned)sv[4 * w + 1] << 16);
        v.y = (unsigned)sv[4 * w + 2] | ((unsigned)sv[4 * w + 3] << 16);
        dst[w] = v;
    }
}

// ---------------------------------------------------------------------------
// K5: fused envsum + interaction matmul + self term.
// Phase 1: wave w accumulates env rows for atoms 4w..4w+3 (lane = feature),
//          4-pair batches (padded CSR) for 4x memory-level parallelism.
// Phase 2: MFMA 16x16x32 bf16: out[16 atoms][64] = env[16][1344] x W[1344][64].
__global__ void __launch_bounds__(256, 3)
k_main(const float* __restrict__ x, const int* __restrict__ offsets,
       const int* __restrict__ s_second, const unsigned short* __restrict__ s_sense,
       const unsigned short* __restrict__ WtB, const float* __restrict__ bself,
       float* __restrict__ out) {
    __shared__ unsigned short env[BA * ESTRIDE];
    const int t  = threadIdx.x;
    const int w  = t >> 6;       // wave 0..3
    const int l  = t & 63;       // lane
    const int a0 = blockIdx.x * BA;

    // ---- Phase 1: envsum ----
    for (int c = 0; c < 4; c++) {
        const int i = 4 * w + c;
        const int a = a0 + i;
        const int beg = offsets[a];
        const int end = offsets[a + 1];      // end-beg is a multiple of 4
        float acc[ND];
        #pragma unroll
        for (int m = 0; m < ND; m++) acc[m] = 0.0f;

        for (int j = beg; j < end; j += 4) {
            int4 bi = *(const int4*)&s_second[j];          // 16B aligned (j%4==0)
            float x0 = x[bi.x * NF + l];
            float x1 = x[bi.y * NF + l];
            float x2 = x[bi.z * NF + l];
            float x3 = x[bi.w * NF + l];
            const uint2* s0 = (const uint2*)(s_sense + (size_t)(j + 0) * ND);
            const uint2* s1 = (const uint2*)(s_sense + (size_t)(j + 1) * ND);
            const uint2* s2 = (const uint2*)(s_sense + (size_t)(j + 2) * ND);
            const uint2* s3 = (const uint2*)(s_sense + (size_t)(j + 3) * ND);
            uint2 v0[5], v1[5], v2[5], v3[5];
            #pragma unroll
            for (int q = 0; q < 5; q++) { v0[q] = s0[q]; v1[q] = s1[q]; v2[q] = s2[q]; v3[q] = s3[q]; }
            #pragma unroll
            for (int q = 0; q < 5; q++) {
                acc[4*q+0] += bf_lo(v0[q].x) * x0;
                acc[4*q+1] += bf_hi(v0[q].x) * x0;
                acc[4*q+2] += bf_lo(v0[q].y) * x0;
                acc[4*q+3] += bf_hi(v0[q].y) * x0;
                acc[4*q+0] += bf_lo(v1[q].x) * x1;
                acc[4*q+1] += bf_hi(v1[q].x) * x1;
                acc[4*q+2] += bf_lo(v1[q].y) * x1;
                acc[4*q+3] += bf_hi(v1[q].y) * x1;
                acc[4*q+0] += bf_lo(v2[q].x) * x2;
                acc[4*q+1] += bf_hi(v2[q].x) * x2;
                acc[4*q+2] += bf_lo(v2[q].y) * x2;
                acc[4*q+3] += bf_hi(v2[q].y) * x2;
                acc[4*q+0] += bf_lo(v3[q].x) * x3;
                acc[4*q+1] += bf_hi(v3[q].x) * x3;
                acc[4*q+2] += bf_lo(v3[q].y) * x3;
                acc[4*q+3] += bf_hi(v3[q].y) * x3;
            }
        }
        unsigned short* er = &env[i * ESTRIDE];
        #pragma unroll
        for (int m = 0; m < ND; m++) er[l + 64 * m] = f2bf(acc[m]);
        er[K_ENV + l] = f2bf(x[a * NF + l]);   // self features as extra K rows
    }
    __syncthreads();

    // ---- Phase 2: MFMA GEMM ----
    const int m16  = l & 15;     // A-row / C-col index
    const int quad = l >> 4;
    f32x4 acc = {0.f, 0.f, 0.f, 0.f};
    for (int ks = 0; ks < NKSTEP; ks++) {
        s16x8 afrag = *(const s16x8*)&env[m16 * ESTRIDE + ks * 32 + quad * 8];
        s16x8 bfrag = *(const s16x8*)&WtB[((ks * 4 + w) * 64 + l) * 8];
        acc = __builtin_amdgcn_mfma_f32_16x16x32_bf16(
                  __builtin_bit_cast(bf16x8, afrag),
                  __builtin_bit_cast(bf16x8, bfrag), acc, 0, 0, 0);
    }
    const float bs = bself[w * 16 + m16];
    #pragma unroll
    for (int r = 0; r < 4; r++) {
        int row = quad * 4 + r;                       // atom within block
        out[(size_t)(a0 + row) * NF + w * 16 + m16] = acc[r] + bs;
    }
}

// ---------------------------------------------------------------------------
extern "C" void kernel_launch(void* const* d_in, const int* in_sizes, int n_in,
                              void* d_out, int out_size, void* d_ws, size_t ws_size,
                              hipStream_t stream) {
    const float* x      = (const float*)d_in[0];
    const int*   first  = (const int*)d_in[1];
    const int*   second = (const int*)d_in[2];
    const float* dist   = (const float*)d_in[3];
    const float* mu     = (const float*)d_in[4];
    const float* sigma  = (const float*)d_in[5];
    const float* iw     = (const float*)d_in[6];
    const float* wself  = (const float*)d_in[7];
    const float* bself  = (const float*)d_in[8];
    float* out = (float*)d_out;

    char* ws = (char*)d_ws;
    unsigned short* WtB      = (unsigned short*)(ws);           // 172032 B
    int*            counts   = (int*)(ws + 172032);             // 120000 B
    int*            cursor   = (int*)(ws + 292032);             // 120000 B (contiguous with counts)
    int*            offsets  = (int*)(ws + 412032);             // 120064 B
    int*            s_second = (int*)(ws + 532096);             // 1680000 B
    float*          s_dist   = (float*)(ws + 2212096);          // 1680000 B
    unsigned short* s_sense  = (unsigned short*)(ws + 3892096); // 16800000 B -> total ~20.7 MB

    k_pack_w<<<dim3(42), dim3(256), 0, stream>>>(iw, wself, WtB);
    k_init<<<dim3((PAD_MAX + 255) / 256), dim3(256), 0, stream>>>(counts, s_second, s_dist);
    k_hist<<<dim3((N_PAIRS + 255) / 256), dim3(256), 0, stream>>>(first, counts);
    k_scan<<<dim3(1), dim3(1024), 0, stream>>>(counts, offsets);
    k_scatter<<<dim3((N_PAIRS + 255) / 256), dim3(256), 0, stream>>>(
        first, second, dist, offsets, cursor, s_second, s_dist);
    k_sense<<<dim3((PAD_MAX + 255) / 256), dim3(256), 0, stream>>>(
        s_dist, mu, sigma, s_sense);
    k_main<<<dim3(N_ATOMS / BA), dim3(256), 0, stream>>>(
        x, offsets, s_second, s_sense, WtB, bself, out);
}